// Round 13
// baseline (111.514 us; speedup 1.0000x reference)
//
#include <hip/hip_runtime.h>

#define NBATCH 32
#define SEQ    2048
#define NU     512
#define ASTR   36   // LDS row stride in shorts (72 B)

typedef __attribute__((ext_vector_type(8)))  short bf16x8;
typedef __attribute__((ext_vector_type(16))) float f32x16;

__device__ __forceinline__ short bf16_rne(float f) {
  union { float f; unsigned u; } v; v.f = f;
  unsigned r = v.u + 0x7fffu + ((v.u >> 16) & 1u);
  return (short)(r >> 16);
}

// pack bf16(lo), bf16(hi) (truncation) into one u32 via a single v_perm_b32
__device__ __forceinline__ unsigned pk2(float lo, float hi) {
  return __builtin_amdgcn_perm(__float_as_uint(hi), __float_as_uint(lo), 0x07060302u);
}

__device__ __forceinline__ float fast_tanh(float x) {
  float ax = __builtin_fabsf(x);
  float t  = __expf(-2.0f * ax);
  float r  = (1.0f - t) / (1.0f + t);
  return x < 0.0f ? -r : r;
}

// ---------- fused prep ----------
__global__ __launch_bounds__(256) void prep_all(const float* __restrict__ W,
                                                const float* __restrict__ sp,
                                                const float* __restrict__ U,
                                                const float* __restrict__ Ub,
                                                const float* __restrict__ Wb,
                                                short* __restrict__ Wt,
                                                float* __restrict__ first) {
  __shared__ float srow[NU];
  if (blockIdx.x < 1024) {
    int idx = blockIdx.x * 256 + threadIdx.x;
    int u = idx >> 9, k = idx & 511;
    Wt[(size_t)u * NU + k] = bf16_rne(W[(size_t)k * NU + u]);
  } else {
    int blk = blockIdx.x - 1024;
    int b = blk >> 1, half = blk & 1, t = threadIdx.x;
    srow[t]       = sp[b * NU + t];
    srow[t + 256] = sp[b * NU + t + 256];
    __syncthreads();
    int col = half * 256 + t;
    float acc = Ub[col] + Wb[col];
    #pragma unroll 8
    for (int k = 0; k < NU; ++k) acc += srow[k] * U[(size_t)k * NU + col];
    first[b * NU + col] = acc;
  }
}

// ---------- main: R12 structure + B depth-2 prefetch + lgkm-only barriers ----------
// 256 rows x 128 cols per block, 8 waves (4 row x 2 col), wave tile 64x64,
// acc[2][2] f32x16 = 64 f32. All vm loads (h + B) issued one full iteration
// before consumption; barriers wait ONLY lgkmcnt(0) (ds_writes) — register-
// destined vm loads stay in flight across the barrier (no vmcnt(0) drain).
__global__ __launch_bounds__(512, 4) void attn_main(
    const float* __restrict__ h,      // (65536, 512) fp32
    const short* __restrict__ Wt,     // (512 cols x 512 k) bf16
    const float* __restrict__ first,  // (B, 512) incl. U_bias + W_bias
    const float* __restrict__ V,      // (512)
    float* __restrict__ s0)           // (65536) score accumulator (pre-zeroed)
{
  __shared__ short Alds[2][256 * ASTR];   // 18.4 KB each
  __shared__ short Blds[2][128 * ASTR];   //  9.2 KB each
  __shared__ float scores_lds[256];

  const int tid  = threadIdx.x;
  const int lane = tid & 63;
  const int w    = tid >> 6;
  const int wr   = w >> 1, wc = w & 1;
  const int l31  = lane & 31, hi = lane >> 5;

  // XCD-aware remap: 4 col-quarters of a row-panel adjacent on one XCD
  const int bid = blockIdx.x;
  const int lb  = (bid & 7) * 128 + (bid >> 3);    // grid 1024 = 8*128, bijective
  const int panel = lb >> 2, q = lb & 3;
  const int rowbase = panel * 256;
  const int b = panel >> 3;

  // staging addresses
  const int arow  = tid >> 1;
  const int ahalf = tid & 1;
  const float* hA = h + (size_t)(rowbase + arow) * NU + ahalf * 16;
  const int awr   = arow * ASTR + ahalf * 16;
  const short* bsrc = Wt + (size_t)(q * 128 + (tid >> 2)) * NU + (tid & 3) * 8;
  const int bwr   = (tid >> 2) * ASTR + (tid & 3) * 8;

  // compute-read bases (shorts)
  const int rA0 = (wr * 64 + l31) * ASTR + hi * 8;
  const int rA1 = rA0 + 32 * ASTR;
  const int rB0 = (wc * 64 + l31) * ASTR + hi * 8;
  const int rB1 = rB0 + 32 * ASTR;

  f32x16 acc[2][2];
  #pragma unroll
  for (int rt = 0; rt < 2; ++rt)
    #pragma unroll
    for (int ct = 0; ct < 2; ++ct)
      #pragma unroll
      for (int r = 0; r < 16; ++r) acc[rt][ct][r] = 0.f;

  float4 ha0, ha1, ha2, ha3;   // h slot a
  float4 hb0, hb1, hb2, hb3;   // h slot b
  int4   bqa, bqb;             // B slots a/b

  #define LOAD_H(V0, V1, V2, V3, ktn)                                       \
    {                                                                       \
      const float* p = hA + (ktn) * 32;                                     \
      V0 = *reinterpret_cast<const float4*>(p + 0);                         \
      V1 = *reinterpret_cast<const float4*>(p + 4);                         \
      V2 = *reinterpret_cast<const float4*>(p + 8);                         \
      V3 = *reinterpret_cast<const float4*>(p + 12);                        \
    }

  #define CVT_WRITE(dst, V0, V1, V2, V3, BQ)                                \
    {                                                                       \
      uint4 u0, u1;                                                         \
      u0.x = pk2(V0.x, V0.y); u0.y = pk2(V0.z, V0.w);                       \
      u0.z = pk2(V1.x, V1.y); u0.w = pk2(V1.z, V1.w);                       \
      u1.x = pk2(V2.x, V2.y); u1.y = pk2(V2.z, V2.w);                       \
      u1.z = pk2(V3.x, V3.y); u1.w = pk2(V3.z, V3.w);                       \
      *reinterpret_cast<uint4*>(&Alds[dst][awr])     = u0;                  \
      *reinterpret_cast<uint4*>(&Alds[dst][awr + 8]) = u1;                  \
      *reinterpret_cast<int4*>(&Blds[dst][bwr])      = BQ;                  \
    }

  #define COMPUTE(cur)                                                      \
    _Pragma("unroll")                                                       \
    for (int ks = 0; ks < 2; ++ks) {                                        \
      bf16x8 af0, af1, bf0, bf1;                                            \
      af0 = *reinterpret_cast<const bf16x8*>(&Alds[cur][rA0 + ks * 16]);    \
      af1 = *reinterpret_cast<const bf16x8*>(&Alds[cur][rA1 + ks * 16]);    \
      bf0 = *reinterpret_cast<const bf16x8*>(&Blds[cur][rB0 + ks * 16]);    \
      bf1 = *reinterpret_cast<const bf16x8*>(&Blds[cur][rB1 + ks * 16]);    \
      acc[0][0] = __builtin_amdgcn_mfma_f32_32x32x16_bf16(af0, bf0, acc[0][0], 0, 0, 0); \
      acc[0][1] = __builtin_amdgcn_mfma_f32_32x32x16_bf16(af0, bf1, acc[0][1], 0, 0, 0); \
      acc[1][0] = __builtin_amdgcn_mfma_f32_32x32x16_bf16(af1, bf0, acc[1][0], 0, 0, 0); \
      acc[1][1] = __builtin_amdgcn_mfma_f32_32x32x16_bf16(af1, bf1, acc[1][1], 0, 0, 0); \
    }

  // lgkm-only barrier: ds_writes must be visible; register-destined vm loads
  // may stay in flight (no vmcnt drain). asm memory clobbers pin LDS ops.
  #define BAR_LGKM                                                          \
    asm volatile("s_waitcnt lgkmcnt(0)" ::: "memory");                      \
    __builtin_amdgcn_s_barrier();                                           \
    asm volatile("" ::: "memory");

  // ---- prologue: tile 0 -> buf0 (slot a), tile 1 -> slot b (in flight)
  bqa = *reinterpret_cast<const int4*>(bsrc);
  LOAD_H(ha0, ha1, ha2, ha3, 0);
  CVT_WRITE(0, ha0, ha1, ha2, ha3, bqa);
  bqb = *reinterpret_cast<const int4*>(bsrc + 1 * 32);
  LOAD_H(hb0, hb1, hb2, hb3, 1);
  BAR_LGKM;

  // ---- main loop: kt = 0..11 in pairs; all loads 1 full iteration ahead
  #pragma unroll 1
  for (int kt2 = 0; kt2 < 6; ++kt2) {
    const int kt = kt2 * 2;
    // even kt: issue tile kt+2 -> slot a; compute buf0; cvt tile kt+1 (slot b) -> buf1
    bqa = *reinterpret_cast<const int4*>(bsrc + (kt + 2) * 32);
    LOAD_H(ha0, ha1, ha2, ha3, kt + 2);
    COMPUTE(0);
    CVT_WRITE(1, hb0, hb1, hb2, hb3, bqb);
    BAR_LGKM;
    // odd kt+1: issue tile kt+3 -> slot b; compute buf1; cvt tile kt+2 (slot a) -> buf0
    bqb = *reinterpret_cast<const int4*>(bsrc + (kt + 3) * 32);
    LOAD_H(hb0, hb1, hb2, hb3, kt + 3);
    COMPUTE(1);
    CVT_WRITE(0, ha0, ha1, ha2, ha3, bqa);
    BAR_LGKM;
  }

  // kt = 12: issue tile 14 -> slot a; compute buf0; cvt tile 13 (slot b) -> buf1
  bqa = *reinterpret_cast<const int4*>(bsrc + 14 * 32);
  LOAD_H(ha0, ha1, ha2, ha3, 14);
  COMPUTE(0);
  CVT_WRITE(1, hb0, hb1, hb2, hb3, bqb);
  BAR_LGKM;

  // kt = 13: issue tile 15 -> slot b; compute buf1; cvt tile 14 (slot a) -> buf0
  bqb = *reinterpret_cast<const int4*>(bsrc + 15 * 32);
  LOAD_H(hb0, hb1, hb2, hb3, 15);
  COMPUTE(1);
  CVT_WRITE(0, ha0, ha1, ha2, ha3, bqa);
  BAR_LGKM;

  // kt = 14: compute buf0; cvt tile 15 (slot b) -> buf1
  COMPUTE(0);
  CVT_WRITE(1, hb0, hb1, hb2, hb3, bqb);
  BAR_LGKM;

  // kt = 15: compute only
  COMPUTE(1);

  #undef LOAD_H
  #undef CVT_WRITE
  #undef COMPUTE
  #undef BAR_LGKM

  // ---- epilogue: tanh + V, reduce over this block's 128 cols -> per-row partials
  float fv[2], vv[2];
  #pragma unroll
  for (int ct = 0; ct < 2; ++ct) {
    int col = q * 128 + wc * 64 + ct * 32 + l31;
    fv[ct] = first[b * NU + col];
    vv[ct] = V[col];
  }
  float part[2][16];
  #pragma unroll
  for (int rt = 0; rt < 2; ++rt) {
    #pragma unroll
    for (int r = 0; r < 16; ++r) {
      float p = 0.f;
      #pragma unroll
      for (int ct = 0; ct < 2; ++ct)
        p += vv[ct] * fast_tanh(fv[ct] + acc[rt][ct][r]);
      #pragma unroll
      for (int m = 1; m < 32; m <<= 1) p += __shfl_xor(p, m, 64);
      part[rt][r] = p;
    }
  }
  __syncthreads();
  if (wc == 0 && l31 == 0) {
    #pragma unroll
    for (int rt = 0; rt < 2; ++rt)
      #pragma unroll
      for (int r = 0; r < 16; ++r)
        scores_lds[wr * 64 + rt * 32 + (r & 3) + 8 * (r >> 2) + 4 * hi] = part[rt][r];
  }
  __syncthreads();
  if (wc == 1 && l31 == 0) {
    #pragma unroll
    for (int rt = 0; rt < 2; ++rt)
      #pragma unroll
      for (int r = 0; r < 16; ++r)
        scores_lds[wr * 64 + rt * 32 + (r & 3) + 8 * (r >> 2) + 4 * hi] += part[rt][r];
  }
  __syncthreads();
  if (tid < 256) atomicAdd(&s0[rowbase + tid], scores_lds[tid]);
}

// ---------- softmax over S per batch (in-place in d_out) + context ----------
__global__ __launch_bounds__(256) void softmax_ctx(const float* __restrict__ sp,
                                                   float* __restrict__ out) {
  const int b = blockIdx.x;
  const int t = threadIdx.x;
  float* wgt = out + NBATCH * NU + (size_t)b * SEQ;
  __shared__ float red[4];

  float v[8];
  float mx = -1e30f;
  #pragma unroll
  for (int i = 0; i < 8; ++i) { v[i] = wgt[t + i * 256]; mx = fmaxf(mx, v[i]); }
  #pragma unroll
  for (int m = 1; m < 64; m <<= 1) mx = fmaxf(mx, __shfl_xor(mx, m, 64));
  if ((t & 63) == 0) red[t >> 6] = mx;
  __syncthreads();
  mx = fmaxf(fmaxf(red[0], red[1]), fmaxf(red[2], red[3]));
  __syncthreads();

  float se = 0.f;
  #pragma unroll
  for (int i = 0; i < 8; ++i) { v[i] = __expf(v[i] - mx); se += v[i]; }
  #pragma unroll
  for (int m = 1; m < 64; m <<= 1) se += __shfl_xor(se, m, 64);
  if ((t & 63) == 0) red[t >> 6] = se;
  __syncthreads();
  se = red[0] + red[1] + red[2] + red[3];
  __syncthreads();

  const float inv = 1.0f / se;
  float sw = 0.f;
  #pragma unroll
  for (int i = 0; i < 8; ++i) { float wi = v[i] * inv; wgt[t + i * 256] = wi; sw += wi; }
  #pragma unroll
  for (int m = 1; m < 64; m <<= 1) sw += __shfl_xor(sw, m, 64);
  if ((t & 63) == 0) red[t >> 6] = sw;
  __syncthreads();
  sw = red[0] + red[1] + red[2] + red[3];

  out[b * NU + t]       = sp[b * NU + t] * sw;
  out[b * NU + t + 256] = sp[b * NU + t + 256] * sw;
}

extern "C" void kernel_launch(void* const* d_in, const int* in_sizes, int n_in,
                              void* d_out, int out_size, void* d_ws, size_t ws_size,
                              hipStream_t stream) {
  (void)in_sizes; (void)n_in; (void)out_size; (void)ws_size;
  const float* s_prev = (const float*)d_in[0];
  const float* h      = (const float*)d_in[1];
  const float* Wk     = (const float*)d_in[2];
  const float* Wb     = (const float*)d_in[3];
  const float* Uk     = (const float*)d_in[4];
  const float* Ub     = (const float*)d_in[5];
  const float* Vk     = (const float*)d_in[6];
  // d_in[7] = V_bias: softmax-shift-invariant, does not affect outputs.

  float* out   = (float*)d_out;
  float* first = (float*)d_ws;                    // 64 KB
  short* Wt    = (short*)((char*)d_ws + 65536);   // 512 KB
  float* s0    = out + NBATCH * NU;               // score accumulator in weights slot

  hipMemsetAsync(s0, 0, (size_t)NBATCH * SEQ * sizeof(float), stream);
  prep_all   <<<1088, 256, 0, stream>>>(Wk, s_prev, Uk, Ub, Wb, Wt, first);
  attn_main  <<<1024, 512, 0, stream>>>(h, Wt, first, Vk, s0);
  softmax_ctx<<<  32, 256, 0, stream>>>(s_prev, out);
}